// Round 21
// baseline (339.965 us; speedup 1.0000x reference)
//
#include <hip/hip_runtime.h>
#include <hip/hip_bf16.h>

typedef __hip_bfloat16 bf16;
typedef __attribute__((ext_vector_type(8))) short short8;
typedef __attribute__((ext_vector_type(4))) float f32x4;
typedef __attribute__((ext_vector_type(2))) float f32x2;

#define NB 128
#define NH 128
#define NLQ 128
#define NLD 512
#define NEMB 300
#define XQROWS 132
#define XDROWS 516
#define XCOLS 320

__device__ __forceinline__ unsigned short bfbits(float x) {
    __hip_bfloat16 h = __float2bfloat16(x);
    return *reinterpret_cast<unsigned short*>(&h);
}

__device__ __forceinline__ float fast_tanh(float x) {
    x = fminf(9.f, fmaxf(-9.f, x));
    float e = __builtin_amdgcn_exp2f(x * 2.8853900817779268f); // e^{2x}
    return (e - 1.f) * __builtin_amdgcn_rcpf(e + 1.f);
}

// ---------------- Stage 0: fused pack (weights + gathered embeddings) -------
__global__ __launch_bounds__(256)
void pack_all(const int* __restrict__ q_tok, const int* __restrict__ d_tok,
              const float* __restrict__ q_emb, const float* __restrict__ d_emb,
              const float* __restrict__ cw0, const float* __restrict__ cw1,
              const float* __restrict__ cw2,
              bf16* __restrict__ Wp, bf16* __restrict__ Xq, bf16* __restrict__ Xd)
{
    int bx = blockIdx.x;
    if (bx < 1440) {                       // ---- weights: 368640 elements ----
        int e = bx * 256 + threadIdx.x;
        int widx = (e >= 204800) ? 2 : (e >= 81920 ? 1 : 0);
        int off = (widx == 0) ? 0 : (widx == 1 ? 81920 : 204800);
        int el = e - off;
        int W = widx + 2;
        int ch = el >> 12;
        int cc = ch / W;
        int t  = ch - cc * W;
        int h  = (el >> 5) & 127;
        int cp = el & 31;
        int c  = cc * 32 + cp;
        const float* cw = (widx == 0) ? cw0 : (widx == 1 ? cw1 : cw2);
        float v = (c < NEMB) ? cw[(h * NEMB + c) * W + t] : 0.f;
        Wp[e] = __float2bfloat16(v);
        return;
    }
    int gid = (bx - 1440) * 256 + threadIdx.x;
    int row = gid / 20, g = gid - row * 20;
    const float* emb; bf16* dst; int tok;
    if (row < NB * XQROWS) {
        int b = row / XQROWS, l = row - b * XQROWS;
        tok = (l < NLQ) ? q_tok[b * NLQ + l] : -1;
        emb = q_emb;
        dst = Xq + (size_t)row * XCOLS + g * 16;
    } else {
        int rowd = row - NB * XQROWS;
        int b = rowd / XDROWS, l = rowd - b * XDROWS;
        tok = (l < NLD) ? d_tok[b * NLD + l] : -1;
        emb = d_emb;
        dst = Xd + (size_t)rowd * XCOLS + g * 16;
    }
    int c0 = g * 16;
    float4 v[4];
    #pragma unroll
    for (int q = 0; q < 4; ++q) {
        int c = c0 + q * 4;
        v[q] = make_float4(0.f, 0.f, 0.f, 0.f);
        if (tok >= 0 && c < NEMB)
            v[q] = *reinterpret_cast<const float4*>(emb + (size_t)tok * NEMB + c);
    }
    short8 o0, o1;
    o0[0] = (short)bfbits(v[0].x); o0[1] = (short)bfbits(v[0].y);
    o0[2] = (short)bfbits(v[0].z); o0[3] = (short)bfbits(v[0].w);
    o0[4] = (short)bfbits(v[1].x); o0[5] = (short)bfbits(v[1].y);
    o0[6] = (short)bfbits(v[1].z); o0[7] = (short)bfbits(v[1].w);
    o1[0] = (short)bfbits(v[2].x); o1[1] = (short)bfbits(v[2].y);
    o1[2] = (short)bfbits(v[2].z); o1[3] = (short)bfbits(v[2].w);
    o1[4] = (short)bfbits(v[3].x); o1[5] = (short)bfbits(v[3].y);
    o1[6] = (short)bfbits(v[3].z); o1[7] = (short)bfbits(v[3].w);
    *reinterpret_cast<short8*>(dst) = o0;
    *reinterpret_cast<short8*>(dst + 8) = o1;
}

// ---------------- Stage 1: conv + tanh + l2norm (round-17, unchanged) ------
__global__ __launch_bounds__(512, 4)
void conv_kernel(const bf16* __restrict__ Xq, const bf16* __restrict__ Xd,
                 const bf16* __restrict__ Wp,
                 const float* __restrict__ cb0, const float* __restrict__ cb1,
                 const float* __restrict__ cb2,
                 bf16* __restrict__ qn, bf16* __restrict__ dn)
{
    __shared__ bf16 Xs[2][2][132][40];
    __shared__ bf16 Bs[2][128][36];
    __shared__ float ssq[2][256];

    int bx = blockIdx.x;
    int widx = bx % 3;
    int inner = bx / 3;
    int W = widx + 2;
    const bf16* wp = Wp + ((widx == 0) ? 0 : (widx == 1 ? 81920 : 204800));
    const float* cb = (widx == 0) ? cb0 : (widx == 1 ? cb1 : cb2);

    int tid = threadIdx.x;
    int lane = tid & 63;
    int wv = tid >> 6;
    int wr = wv >> 1;
    int wc = wv & 1;
    int s_wave = wr >> 1;
    int lr_base = (wr & 1) * 64;

    bf16* outp; int L;
    int sb0, sb1, sl00, sl01;
    const bf16* xbase;
    size_t grow0, grow1;
    if (inner < 64) {
        outp = qn + (size_t)widx * NB * NLQ * NH;
        L = NLQ; sb0 = inner * 2; sb1 = sb0 + 1; sl00 = 0; sl01 = 0;
        xbase = Xq; grow0 = (size_t)sb0 * XQROWS; grow1 = (size_t)sb1 * XQROWS;
    } else {
        int i = inner - 64;
        outp = dn + (size_t)widx * NB * NLD * NH;
        L = NLD; sb0 = i >> 1; sb1 = sb0; sl00 = (i & 1) * 256; sl01 = sl00 + 128;
        xbase = Xd; grow0 = (size_t)sb0 * XDROWS + sl00; grow1 = grow0 + 128;
    }

    int sr = tid >> 2;
    int colg = tid & 3;
    const bf16* gsrc0 = xbase + (grow0 + sr) * XCOLS + colg * 8;
    const bf16* gsrc1 = xbase + (grow1 + sr) * XCOLS + colg * 8;
    bool has_tail = (tid >= 448 && tid < 480);
    int j = tid - 448;
    int ts = (j >> 2) >> 2, trr = 128 + ((j >> 2) & 3), tcolg = j & 3;
    const bf16* gsrcT = xbase + ((ts ? grow1 : grow0) + trr) * XCOLS + tcolg * 8;

    const short8* wp8 = reinterpret_cast<const short8*>(wp);
    int bh = tid >> 2, bcg = tid & 3;

    {
        short8 a0 = *reinterpret_cast<const short8*>(gsrc0);
        short8 a1 = *reinterpret_cast<const short8*>(gsrc1);
        short8 at;
        if (has_tail) at = *reinterpret_cast<const short8*>(gsrcT);
        short8 b0 = wp8[tid];
        *reinterpret_cast<short8*>(&Xs[0][0][sr][colg * 8]) = a0;
        *reinterpret_cast<short8*>(&Xs[0][1][sr][colg * 8]) = a1;
        if (has_tail) *reinterpret_cast<short8*>(&Xs[0][ts][trr][tcolg * 8]) = at;
        *reinterpret_cast<short8*>(&Bs[0][bh][bcg * 8]) = b0;
    }
    __syncthreads();

    f32x4 acc[4][4];
    #pragma unroll
    for (int m = 0; m < 4; ++m)
        #pragma unroll
        for (int n = 0; n < 4; ++n)
            acc[m][n] = (f32x4){0.f, 0.f, 0.f, 0.f};

    int nsteps = W * 10;
    int xcur = 0, bcur = 0, step = 0;
    short8 a0, a1, at;
    for (int cc = 0; cc < 10; ++cc) {
        if (cc < 9) {
            a0 = *reinterpret_cast<const short8*>(gsrc0 + (cc + 1) * 32);
            a1 = *reinterpret_cast<const short8*>(gsrc1 + (cc + 1) * 32);
            if (has_tail) at = *reinterpret_cast<const short8*>(gsrcT + (cc + 1) * 32);
        }
        for (int t = 0; t < W; ++t, ++step) {
            short8 nb;
            bool hn = (step + 1 < nsteps);
            if (hn) nb = wp8[(size_t)(step + 1) * 512 + tid];

            short8 bv[4], af[4];
            #pragma unroll
            for (int n = 0; n < 4; ++n)
                bv[n] = *reinterpret_cast<const short8*>(
                    &Bs[bcur][wc * 64 + n * 16 + (lane & 15)][(lane >> 4) * 8]);
            #pragma unroll
            for (int m = 0; m < 4; ++m)
                af[m] = *reinterpret_cast<const short8*>(
                    &Xs[xcur][s_wave][lr_base + m * 16 + (lane & 15) + t][(lane >> 4) * 8]);
            #pragma unroll
            for (int m = 0; m < 4; ++m)
                #pragma unroll
                for (int n = 0; n < 4; ++n)
                    acc[m][n] = __builtin_amdgcn_mfma_f32_16x16x32_bf16(af[m], bv[n], acc[m][n], 0, 0, 0);

            if (hn)
                *reinterpret_cast<short8*>(&Bs[bcur ^ 1][bh][bcg * 8]) = nb;
            if (t == W - 1 && cc < 9) {
                *reinterpret_cast<short8*>(&Xs[xcur ^ 1][0][sr][colg * 8]) = a0;
                *reinterpret_cast<short8*>(&Xs[xcur ^ 1][1][sr][colg * 8]) = a1;
                if (has_tail) *reinterpret_cast<short8*>(&Xs[xcur ^ 1][ts][trr][tcolg * 8]) = at;
            }
            if (hn || (t == W - 1 && cc < 9)) __syncthreads();
            bcur ^= 1;
            if (t == W - 1) xcur ^= 1;
        }
    }

    float ssl[4][4];
    #pragma unroll
    for (int m = 0; m < 4; ++m)
        #pragma unroll
        for (int i = 0; i < 4; ++i) ssl[m][i] = 0.f;

    #pragma unroll
    for (int n = 0; n < 4; ++n) {
        float bias = cb[wc * 64 + n * 16 + (lane & 15)];
        #pragma unroll
        for (int m = 0; m < 4; ++m)
            #pragma unroll
            for (int i = 0; i < 4; ++i) {
                float v = fast_tanh(acc[m][n][i] + bias);
                acc[m][n][i] = v;
                ssl[m][i] += v * v;
            }
    }
    #pragma unroll
    for (int m = 0; m < 4; ++m)
        #pragma unroll
        for (int i = 0; i < 4; ++i) {
            float s = ssl[m][i];
            s += __shfl_xor(s, 1); s += __shfl_xor(s, 2);
            s += __shfl_xor(s, 4); s += __shfl_xor(s, 8);
            ssl[m][i] = s;
        }
    if ((lane & 15) == 0) {
        #pragma unroll
        for (int m = 0; m < 4; ++m)
            #pragma unroll
            for (int i = 0; i < 4; ++i)
                ssq[wc][wr * 64 + m * 16 + (lane >> 4) * 4 + i] = ssl[m][i];
    }
    __syncthreads();
    #pragma unroll
    for (int m = 0; m < 4; ++m)
        #pragma unroll
        for (int i = 0; i < 4; ++i) {
            int r = wr * 64 + m * 16 + (lane >> 4) * 4 + i;
            float s2 = ssq[0][r] + ssq[1][r];
            float sc = 1.f / fmaxf(sqrtf(s2), 1e-12f);
            int s = r >> 7, lr = r & 127;
            int b = s ? sb1 : sb0;
            int l = (s ? sl01 : sl00) + lr;
            bf16* dst = outp + ((size_t)(b * L + l)) * NH;
            #pragma unroll
            for (int n = 0; n < 4; ++n)
                dst[wc * 64 + n * 16 + (lane & 15)] = __float2bfloat16(acc[m][n][i] * sc);
        }
}

// ---------------- Stage 2: sim -- T15 double-pipeline ----------
// Two named acc states: chunk cc's MFMA fills one while the pooling VALU
// consumes the OTHER (chunk cc-1). Breaks the in-wave MFMA->pooling serial
// dependency; matrix and VALU pipes co-issue. Unroll-by-2, static indexing.
__global__ __launch_bounds__(512, 4)
void sim_kernel(const bf16* __restrict__ qn, const bf16* __restrict__ dn,
                float* __restrict__ phi_part)
{
    __shared__ bf16 QDs[2][64][136];
    bf16* flat = &QDs[0][0][0];
    float (*red)[64][11] = reinterpret_cast<float(*)[64][11]>(flat); // alias, post-loop

    int blk = blockIdx.x;
    int b = blk / 18;
    int rem = blk - b * 18;
    int pair = rem >> 1;
    int half = rem & 1;
    int qi = pair / 3, di = pair - qi * 3;

    int tid = threadIdx.x, lane = tid & 63, wv = tid >> 6;
    int wr = wv >> 2;     // 0..1 : 32-row ld group
    int wc = wv & 3;      // 0..3 : 16-col lq group

    const bf16* qbase = qn + ((size_t)qi * NB + b) * (NLQ * NH) + (size_t)half * 64 * NH;
    const bf16* dbase = dn + ((size_t)di * NB + b) * (NLD * NH);

    {
        int r = tid >> 3, h0 = (tid & 7) * 16;
        *reinterpret_cast<short8*>(flat + r * 136 + h0) =
            *reinterpret_cast<const short8*>(qbase + (size_t)r * NH + h0);
        *reinterpret_cast<short8*>(flat + r * 136 + h0 + 8) =
            *reinterpret_cast<const short8*>(qbase + (size_t)r * NH + h0 + 8);
    }
    __syncthreads();

    short8 bq[4];
    #pragma unroll
    for (int kc = 0; kc < 4; ++kc)
        bq[kc] = *reinterpret_cast<const short8*>(
            flat + (wc * 16 + (lane & 15)) * 136 + kc * 32 + (lane >> 4) * 8);
    __syncthreads();

    int dr = tid >> 3, dc = (tid & 7) * 16;
    {
        short8 st0 = *reinterpret_cast<const short8*>(dbase + (size_t)dr * NH + dc);
        short8 st1 = *reinterpret_cast<const short8*>(dbase + (size_t)dr * NH + dc + 8);
        *reinterpret_cast<short8*>(&QDs[0][dr][dc]) = st0;
        *reinterpret_cast<short8*>(&QDs[0][dr][dc + 8]) = st1;
    }
    __syncthreads();

    f32x2 sums2[11];
    #pragma unroll
    for (int k = 0; k < 11; ++k) sums2[k] = (f32x2){0.f, 0.f};

    // MFMA one chunk from QDs[cur] into acc2[0..1]
    auto do_mfma = [&](int cur, f32x4* acc2) {
        acc2[0] = (f32x4){0.f, 0.f, 0.f, 0.f};
        acc2[1] = (f32x4){0.f, 0.f, 0.f, 0.f};
        #pragma unroll
        for (int kc = 0; kc < 4; ++kc) {
            short8 af0 = *reinterpret_cast<const short8*>(
                &QDs[cur][wr * 32 + (lane & 15)][kc * 32 + (lane >> 4) * 8]);
            short8 af1 = *reinterpret_cast<const short8*>(
                &QDs[cur][wr * 32 + 16 + (lane & 15)][kc * 32 + (lane >> 4) * 8]);
            acc2[0] = __builtin_amdgcn_mfma_f32_16x16x32_bf16(af0, bq[kc], acc2[0], 0, 0, 0);
            acc2[1] = __builtin_amdgcn_mfma_f32_16x16x32_bf16(af1, bq[kc], acc2[1], 0, 0, 0);
        }
    };
    // branchless pooling on one acc pair (prev chunk)
    auto do_pool = [&](const f32x4* acc2) {
        f32x2 cmax = (f32x2){-2.f, -2.f};
        #pragma unroll
        for (int i = 0; i < 4; ++i) {
            f32x2 x2;
            x2.x = acc2[0][i];
            x2.y = acc2[1][i];
            cmax.x = fmaxf(cmax.x, x2.x);
            cmax.y = fmaxf(cmax.y, x2.y);
            f32x2 ax = x2 * 28.853900817779268f;
            f32x2 R, Ri, E4;
            R.x = __builtin_amdgcn_exp2f(ax.x);
            R.y = __builtin_amdgcn_exp2f(ax.y);
            Ri.x = __builtin_amdgcn_exp2f(-ax.x);
            Ri.y = __builtin_amdgcn_exp2f(-ax.y);
            f32x2 d4 = x2 + 0.1f;
            f32x2 t = d4 * d4 * (-72.134752044448169f);
            E4.x = __builtin_amdgcn_exp2f(t.x);
            E4.y = __builtin_amdgcn_exp2f(t.y);
            sums2[4] += E4;
            f32x2 u = E4 * R;
            sums2[5] += u;
            u *= R; sums2[6] += u;
            u *= R; sums2[7] += u;
            u *= R; sums2[8] += u;
            u *= R; sums2[9] += u;
            f32x2 w = E4 * Ri;
            sums2[3] += w;
            w *= Ri; sums2[2] += w;
            w *= Ri; sums2[1] += w;
            w *= Ri; sums2[0] += w;
        }
        if (__any(fmaxf(cmax.x, cmax.y) > 0.98f)) {   // ~never taken
            #pragma unroll
            for (int i = 0; i < 4; ++i) {
                f32x2 x2;
                x2.x = acc2[0][i];
                x2.y = acc2[1][i];
                f32x2 d1 = x2 - 1.0f;
                f32x2 t1 = d1 * d1 * (-721347.52044448f);
                f32x2 e;
                e.x = __builtin_amdgcn_exp2f(t1.x);
                e.y = __builtin_amdgcn_exp2f(t1.y);
                sums2[10] += e;
            }
        }
    };
    auto stage_next = [&](int cc, int cur) {   // load chunk cc+1, write QDs[cur^1]
        short8 st0 = *reinterpret_cast<const short8*>(dbase + (size_t)((cc + 1) * 64 + dr) * NH + dc);
        short8 st1 = *reinterpret_cast<const short8*>(dbase + (size_t)((cc + 1) * 64 + dr) * NH + dc + 8);
        *reinterpret_cast<short8*>(&QDs[cur ^ 1][dr][dc]) = st0;
        *reinterpret_cast<short8*>(&QDs[cur ^ 1][dr][dc + 8]) = st1;
    };

    f32x4 accA[2], accB[2];

    // prologue: chunk 0 -> accA (no pooling yet)
    do_mfma(0, accA);
    stage_next(0, 0);
    __syncthreads();
    int cur = 1;

    #pragma unroll
    for (int it = 1; it < 8; it += 2) {
        // odd chunk it -> accB, pool accA (chunk it-1)
        do_mfma(cur, accB);
        if (it < 7) stage_next(it, cur);
        do_pool(accA);
        __syncthreads();
        cur ^= 1;
        // even chunk it+1 -> accA, pool accB (chunk it)
        if (it + 1 < 8) {
            do_mfma(cur, accA);
            if (it + 1 < 7) stage_next(it + 1, cur);
            do_pool(accB);
            __syncthreads();
            cur ^= 1;
        }
    }
    do_pool(accB);   // chunk 7

    #pragma unroll
    for (int k = 0; k < 11; ++k) {
        float s = sums2[k].x + sums2[k].y;
        s += __shfl_xor(s, 16);
        s += __shfl_xor(s, 32);
        sums2[k].x = s;
    }
    if ((lane >> 4) == 0) {
        #pragma unroll
        for (int k = 0; k < 11; ++k)
            red[wr][wc * 16 + (lane & 15)][k] = sums2[k].x;
    }
    __syncthreads();

    if (tid < 64) {
        const float scale[11] = {
            4.2483542552915889e-18f,  // e^-40
            3.7751345442790977e-11f,  // e^-24
            6.1442123533282098e-6f,   // e^-12
            1.8315638888734179e-2f,   // e^-4
            1.f, 1.f,
            1.8315638888734179e-2f,   // e^-4
            6.1442123533282098e-6f,   // e^-12
            3.7751345442790977e-11f,  // e^-24
            4.2483542552915889e-18f,  // e^-40
            1.f };
        float lv[11];
        #pragma unroll
        for (int k = 0; k < 11; ++k)
            lv[k] = log1pf(scale[k] * (red[0][tid][k] + red[1][tid][k]));
        #pragma unroll
        for (int k = 0; k < 11; ++k) {
            float s = lv[k];
            s += __shfl_xor(s, 1); s += __shfl_xor(s, 2); s += __shfl_xor(s, 4);
            s += __shfl_xor(s, 8); s += __shfl_xor(s, 16); s += __shfl_xor(s, 32);
            lv[k] = s;
        }
        if (tid == 0) {
            #pragma unroll
            for (int k = 0; k < 11; ++k)
                phi_part[(size_t)blk * 11 + k] = lv[k];
        }
    }
}

// ---------------- Stage 3: final linear (sums the two lq-half partials) -----
__global__ void final_kernel(const float* __restrict__ phi_part,
                             const float* __restrict__ ow,
                             const float* __restrict__ obias, float* __restrict__ out)
{
    int b = threadIdx.x;
    float s = obias[0];
    #pragma unroll
    for (int pair = 0; pair < 9; ++pair)
        #pragma unroll
        for (int k = 0; k < 11; ++k) {
            size_t base = ((size_t)b * 18 + pair * 2) * 11 + k;
            s += (phi_part[base] + phi_part[base + 11]) * ow[pair * 11 + k];
        }
    out[b] = s;
}

extern "C" void kernel_launch(void* const* d_in, const int* in_sizes, int n_in,
                              void* d_out, int out_size, void* d_ws, size_t ws_size,
                              hipStream_t stream)
{
    const int*   query = (const int*)d_in[0];
    const int*   doc   = (const int*)d_in[1];
    const float* q_emb = (const float*)d_in[2];
    const float* d_emb = (const float*)d_in[3];
    const float* out_w = (const float*)d_in[4];
    const float* out_b = (const float*)d_in[5];
    const float* cw0 = (const float*)d_in[6];
    const float* cb0 = (const float*)d_in[7];
    const float* cw1 = (const float*)d_in[8];
    const float* cb1 = (const float*)d_in[9];
    const float* cw2 = (const float*)d_in[10];
    const float* cb2 = (const float*)d_in[11];

    const size_t QN = (size_t)NB * NLQ * NH;
    const size_t DN = (size_t)NB * NLD * NH;
    const size_t XQN = (size_t)NB * XQROWS * XCOLS;
    const size_t XDN = (size_t)NB * XDROWS * XCOLS;

    bf16* Wp = (bf16*)d_ws;
    bf16* Xq = Wp + 368640;
    bf16* Xd = Xq + XQN;
    bf16* qn = Xd + XDN;
    bf16* dn = qn + 3 * QN;
    float* phi_part = (float*)(dn + 3 * DN);

    pack_all<<<7920, 256, 0, stream>>>(query, doc, q_emb, d_emb, cw0, cw1, cw2, Wp, Xq, Xd);
    conv_kernel<<<960, 512, 0, stream>>>(Xq, Xd, Wp, cb0, cb1, cb2, qn, dn);
    sim_kernel<<<NB * 9 * 2, 512, 0, stream>>>(qn, dn, phi_part);
    final_kernel<<<1, 128, 0, stream>>>(phi_part, out_w, out_b, (float*)d_out);
}

// Round 22
// 204.452 us; speedup vs baseline: 1.6628x; 1.6628x over previous
//
#include <hip/hip_runtime.h>
#include <hip/hip_bf16.h>

typedef __hip_bfloat16 bf16;
typedef __attribute__((ext_vector_type(8))) short short8;
typedef __attribute__((ext_vector_type(4))) float f32x4;
typedef __attribute__((ext_vector_type(2))) float f32x2;

#define NB 128
#define NH 128
#define NLQ 128
#define NLD 512
#define NEMB 300
#define XQROWS 132
#define XDROWS 516
#define XCOLS 320

__device__ __forceinline__ unsigned short bfbits(float x) {
    __hip_bfloat16 h = __float2bfloat16(x);
    return *reinterpret_cast<unsigned short*>(&h);
}

__device__ __forceinline__ float fast_tanh(float x) {
    x = fminf(9.f, fmaxf(-9.f, x));
    float e = __builtin_amdgcn_exp2f(x * 2.8853900817779268f); // e^{2x}
    return (e - 1.f) * __builtin_amdgcn_rcpf(e + 1.f);
}

// ---------------- Stage 0: fused pack (weights + gathered embeddings) -------
__global__ __launch_bounds__(256)
void pack_all(const int* __restrict__ q_tok, const int* __restrict__ d_tok,
              const float* __restrict__ q_emb, const float* __restrict__ d_emb,
              const float* __restrict__ cw0, const float* __restrict__ cw1,
              const float* __restrict__ cw2,
              bf16* __restrict__ Wp, bf16* __restrict__ Xq, bf16* __restrict__ Xd)
{
    int bx = blockIdx.x;
    if (bx < 1440) {                       // ---- weights: 368640 elements ----
        int e = bx * 256 + threadIdx.x;
        int widx = (e >= 204800) ? 2 : (e >= 81920 ? 1 : 0);
        int off = (widx == 0) ? 0 : (widx == 1 ? 81920 : 204800);
        int el = e - off;
        int W = widx + 2;
        int ch = el >> 12;
        int cc = ch / W;
        int t  = ch - cc * W;
        int h  = (el >> 5) & 127;
        int cp = el & 31;
        int c  = cc * 32 + cp;
        const float* cw = (widx == 0) ? cw0 : (widx == 1 ? cw1 : cw2);
        float v = (c < NEMB) ? cw[(h * NEMB + c) * W + t] : 0.f;
        Wp[e] = __float2bfloat16(v);
        return;
    }
    int gid = (bx - 1440) * 256 + threadIdx.x;
    int row = gid / 20, g = gid - row * 20;
    const float* emb; bf16* dst; int tok;
    if (row < NB * XQROWS) {
        int b = row / XQROWS, l = row - b * XQROWS;
        tok = (l < NLQ) ? q_tok[b * NLQ + l] : -1;
        emb = q_emb;
        dst = Xq + (size_t)row * XCOLS + g * 16;
    } else {
        int rowd = row - NB * XQROWS;
        int b = rowd / XDROWS, l = rowd - b * XDROWS;
        tok = (l < NLD) ? d_tok[b * NLD + l] : -1;
        emb = d_emb;
        dst = Xd + (size_t)rowd * XCOLS + g * 16;
    }
    int c0 = g * 16;
    float4 v[4];
    #pragma unroll
    for (int q = 0; q < 4; ++q) {
        int c = c0 + q * 4;
        v[q] = make_float4(0.f, 0.f, 0.f, 0.f);
        if (tok >= 0 && c < NEMB)
            v[q] = *reinterpret_cast<const float4*>(emb + (size_t)tok * NEMB + c);
    }
    short8 o0, o1;
    o0[0] = (short)bfbits(v[0].x); o0[1] = (short)bfbits(v[0].y);
    o0[2] = (short)bfbits(v[0].z); o0[3] = (short)bfbits(v[0].w);
    o0[4] = (short)bfbits(v[1].x); o0[5] = (short)bfbits(v[1].y);
    o0[6] = (short)bfbits(v[1].z); o0[7] = (short)bfbits(v[1].w);
    o1[0] = (short)bfbits(v[2].x); o1[1] = (short)bfbits(v[2].y);
    o1[2] = (short)bfbits(v[2].z); o1[3] = (short)bfbits(v[2].w);
    o1[4] = (short)bfbits(v[3].x); o1[5] = (short)bfbits(v[3].y);
    o1[6] = (short)bfbits(v[3].z); o1[7] = (short)bfbits(v[3].w);
    *reinterpret_cast<short8*>(dst) = o0;
    *reinterpret_cast<short8*>(dst + 8) = o1;
}

// ---------------- Stage 1: conv + tanh + l2norm (round-17 structure) --------
__global__ __launch_bounds__(512, 4)
void conv_kernel(const bf16* __restrict__ Xq, const bf16* __restrict__ Xd,
                 const bf16* __restrict__ Wp,
                 const float* __restrict__ cb0, const float* __restrict__ cb1,
                 const float* __restrict__ cb2,
                 bf16* __restrict__ qn, bf16* __restrict__ dn)
{
    __shared__ bf16 Xs[2][2][132][40];
    __shared__ bf16 Bs[2][128][36];
    __shared__ float ssq[2][256];

    int bx = blockIdx.x;
    int widx = bx % 3;
    int inner = bx / 3;
    int W = widx + 2;
    const bf16* wp = Wp + ((widx == 0) ? 0 : (widx == 1 ? 81920 : 204800));
    const float* cb = (widx == 0) ? cb0 : (widx == 1 ? cb1 : cb2);

    int tid = threadIdx.x;
    int lane = tid & 63;
    int wv = tid >> 6;
    int wr = wv >> 1;
    int wc = wv & 1;
    int s_wave = wr >> 1;
    int lr_base = (wr & 1) * 64;

    bf16* outp; int L;
    int sb0, sb1, sl00, sl01;
    const bf16* xbase;
    size_t grow0, grow1;
    if (inner < 64) {
        outp = qn + (size_t)widx * NB * NLQ * NH;
        L = NLQ; sb0 = inner * 2; sb1 = sb0 + 1; sl00 = 0; sl01 = 0;
        xbase = Xq; grow0 = (size_t)sb0 * XQROWS; grow1 = (size_t)sb1 * XQROWS;
    } else {
        int i = inner - 64;
        outp = dn + (size_t)widx * NB * NLD * NH;
        L = NLD; sb0 = i >> 1; sb1 = sb0; sl00 = (i & 1) * 256; sl01 = sl00 + 128;
        xbase = Xd; grow0 = (size_t)sb0 * XDROWS + sl00; grow1 = grow0 + 128;
    }

    int sr = tid >> 2;
    int colg = tid & 3;
    const bf16* gsrc0 = xbase + (grow0 + sr) * XCOLS + colg * 8;
    const bf16* gsrc1 = xbase + (grow1 + sr) * XCOLS + colg * 8;
    bool has_tail = (tid >= 448 && tid < 480);
    int j = tid - 448;
    int ts = (j >> 2) >> 2, trr = 128 + ((j >> 2) & 3), tcolg = j & 3;
    const bf16* gsrcT = xbase + ((ts ? grow1 : grow0) + trr) * XCOLS + tcolg * 8;

    const short8* wp8 = reinterpret_cast<const short8*>(wp);
    int bh = tid >> 2, bcg = tid & 3;

    {
        short8 a0 = *reinterpret_cast<const short8*>(gsrc0);
        short8 a1 = *reinterpret_cast<const short8*>(gsrc1);
        short8 at;
        if (has_tail) at = *reinterpret_cast<const short8*>(gsrcT);
        short8 b0 = wp8[tid];
        *reinterpret_cast<short8*>(&Xs[0][0][sr][colg * 8]) = a0;
        *reinterpret_cast<short8*>(&Xs[0][1][sr][colg * 8]) = a1;
        if (has_tail) *reinterpret_cast<short8*>(&Xs[0][ts][trr][tcolg * 8]) = at;
        *reinterpret_cast<short8*>(&Bs[0][bh][bcg * 8]) = b0;
    }
    __syncthreads();

    f32x4 acc[4][4];
    #pragma unroll
    for (int m = 0; m < 4; ++m)
        #pragma unroll
        for (int n = 0; n < 4; ++n)
            acc[m][n] = (f32x4){0.f, 0.f, 0.f, 0.f};

    int nsteps = W * 10;
    int xcur = 0, bcur = 0, step = 0;
    short8 a0, a1, at;
    for (int cc = 0; cc < 10; ++cc) {
        if (cc < 9) {
            a0 = *reinterpret_cast<const short8*>(gsrc0 + (cc + 1) * 32);
            a1 = *reinterpret_cast<const short8*>(gsrc1 + (cc + 1) * 32);
            if (has_tail) at = *reinterpret_cast<const short8*>(gsrcT + (cc + 1) * 32);
        }
        for (int t = 0; t < W; ++t, ++step) {
            short8 nb;
            bool hn = (step + 1 < nsteps);
            if (hn) nb = wp8[(size_t)(step + 1) * 512 + tid];

            short8 bv[4], af[4];
            #pragma unroll
            for (int n = 0; n < 4; ++n)
                bv[n] = *reinterpret_cast<const short8*>(
                    &Bs[bcur][wc * 64 + n * 16 + (lane & 15)][(lane >> 4) * 8]);
            #pragma unroll
            for (int m = 0; m < 4; ++m)
                af[m] = *reinterpret_cast<const short8*>(
                    &Xs[xcur][s_wave][lr_base + m * 16 + (lane & 15) + t][(lane >> 4) * 8]);
            #pragma unroll
            for (int m = 0; m < 4; ++m)
                #pragma unroll
                for (int n = 0; n < 4; ++n)
                    acc[m][n] = __builtin_amdgcn_mfma_f32_16x16x32_bf16(af[m], bv[n], acc[m][n], 0, 0, 0);

            if (hn)
                *reinterpret_cast<short8*>(&Bs[bcur ^ 1][bh][bcg * 8]) = nb;
            if (t == W - 1 && cc < 9) {
                *reinterpret_cast<short8*>(&Xs[xcur ^ 1][0][sr][colg * 8]) = a0;
                *reinterpret_cast<short8*>(&Xs[xcur ^ 1][1][sr][colg * 8]) = a1;
                if (has_tail) *reinterpret_cast<short8*>(&Xs[xcur ^ 1][ts][trr][tcolg * 8]) = at;
            }
            if (hn || (t == W - 1 && cc < 9)) __syncthreads();
            bcur ^= 1;
            if (t == W - 1) xcur ^= 1;
        }
    }

    float ssl[4][4];
    #pragma unroll
    for (int m = 0; m < 4; ++m)
        #pragma unroll
        for (int i = 0; i < 4; ++i) ssl[m][i] = 0.f;

    #pragma unroll
    for (int n = 0; n < 4; ++n) {
        float bias = cb[wc * 64 + n * 16 + (lane & 15)];
        #pragma unroll
        for (int m = 0; m < 4; ++m)
            #pragma unroll
            for (int i = 0; i < 4; ++i) {
                float v = fast_tanh(acc[m][n][i] + bias);
                acc[m][n][i] = v;
                ssl[m][i] += v * v;
            }
    }
    #pragma unroll
    for (int m = 0; m < 4; ++m)
        #pragma unroll
        for (int i = 0; i < 4; ++i) {
            float s = ssl[m][i];
            s += __shfl_xor(s, 1); s += __shfl_xor(s, 2);
            s += __shfl_xor(s, 4); s += __shfl_xor(s, 8);
            ssl[m][i] = s;
        }
    if ((lane & 15) == 0) {
        #pragma unroll
        for (int m = 0; m < 4; ++m)
            #pragma unroll
            for (int i = 0; i < 4; ++i)
                ssq[wc][wr * 64 + m * 16 + (lane >> 4) * 4 + i] = ssl[m][i];
    }
    __syncthreads();
    #pragma unroll
    for (int m = 0; m < 4; ++m)
        #pragma unroll
        for (int i = 0; i < 4; ++i) {
            int r = wr * 64 + m * 16 + (lane >> 4) * 4 + i;
            float s2 = ssq[0][r] + ssq[1][r];
            float sc = 1.f / fmaxf(sqrtf(s2), 1e-12f);
            int s = r >> 7, lr = r & 127;
            int b = s ? sb1 : sb0;
            int l = (s ? sl01 : sl00) + lr;
            bf16* dst = outp + ((size_t)(b * L + l)) * NH;
            #pragma unroll
            for (int n = 0; n < 4; ++n)
                dst[wc * 64 + n * 16 + (lane & 15)] = __float2bfloat16(acc[m][n][i] * sc);
        }
}

// ---------------- Stage 2: sim -- round-20 (branchless pooling) -------------
__global__ __launch_bounds__(512, 4)
void sim_kernel(const bf16* __restrict__ qn, const bf16* __restrict__ dn,
                float* __restrict__ phi_part)
{
    __shared__ bf16 QDs[2][64][136];
    bf16* flat = &QDs[0][0][0];
    float (*red)[64][11] = reinterpret_cast<float(*)[64][11]>(flat); // alias, post-loop

    int blk = blockIdx.x;
    int b = blk / 18;
    int rem = blk - b * 18;
    int pair = rem >> 1;
    int half = rem & 1;
    int qi = pair / 3, di = pair - qi * 3;

    int tid = threadIdx.x, lane = tid & 63, wv = tid >> 6;
    int wr = wv >> 2;     // 0..1 : 32-row ld group
    int wc = wv & 3;      // 0..3 : 16-col lq group

    const bf16* qbase = qn + ((size_t)qi * NB + b) * (NLQ * NH) + (size_t)half * 64 * NH;
    const bf16* dbase = dn + ((size_t)di * NB + b) * (NLD * NH);

    {
        int r = tid >> 3, h0 = (tid & 7) * 16;
        *reinterpret_cast<short8*>(flat + r * 136 + h0) =
            *reinterpret_cast<const short8*>(qbase + (size_t)r * NH + h0);
        *reinterpret_cast<short8*>(flat + r * 136 + h0 + 8) =
            *reinterpret_cast<const short8*>(qbase + (size_t)r * NH + h0 + 8);
    }
    __syncthreads();

    short8 bq[4];
    #pragma unroll
    for (int kc = 0; kc < 4; ++kc)
        bq[kc] = *reinterpret_cast<const short8*>(
            flat + (wc * 16 + (lane & 15)) * 136 + kc * 32 + (lane >> 4) * 8);
    __syncthreads();

    int dr = tid >> 3, dc = (tid & 7) * 16;
    {
        short8 st0 = *reinterpret_cast<const short8*>(dbase + (size_t)dr * NH + dc);
        short8 st1 = *reinterpret_cast<const short8*>(dbase + (size_t)dr * NH + dc + 8);
        *reinterpret_cast<short8*>(&QDs[0][dr][dc]) = st0;
        *reinterpret_cast<short8*>(&QDs[0][dr][dc + 8]) = st1;
    }
    __syncthreads();

    f32x2 sums2[11];
    #pragma unroll
    for (int k = 0; k < 11; ++k) sums2[k] = (f32x2){0.f, 0.f};

    int cur = 0;
    for (int cc = 0; cc < 8; ++cc) {
        short8 st0, st1;
        if (cc < 7) {
            st0 = *reinterpret_cast<const short8*>(dbase + (size_t)((cc + 1) * 64 + dr) * NH + dc);
            st1 = *reinterpret_cast<const short8*>(dbase + (size_t)((cc + 1) * 64 + dr) * NH + dc + 8);
        }

        f32x4 acc[2];
        acc[0] = (f32x4){0.f, 0.f, 0.f, 0.f};
        acc[1] = (f32x4){0.f, 0.f, 0.f, 0.f};

        #pragma unroll
        for (int kc = 0; kc < 4; ++kc) {
            short8 af[2];
            #pragma unroll
            for (int m = 0; m < 2; ++m)
                af[m] = *reinterpret_cast<const short8*>(
                    &QDs[cur][wr * 32 + m * 16 + (lane & 15)][kc * 32 + (lane >> 4) * 8]);
            #pragma unroll
            for (int m = 0; m < 2; ++m)
                acc[m] = __builtin_amdgcn_mfma_f32_16x16x32_bf16(af[m], bq[kc], acc[m], 0, 0, 0);
        }

        if (cc < 7) {
            *reinterpret_cast<short8*>(&QDs[cur ^ 1][dr][dc]) = st0;
            *reinterpret_cast<short8*>(&QDs[cur ^ 1][dr][dc + 8]) = st1;
        }

        // branchless pooling; chunk-max tracked for the rare exact-kernel pass
        f32x2 cmax = (f32x2){-2.f, -2.f};
        #pragma unroll
        for (int i = 0; i < 4; ++i) {
            f32x2 x2;
            x2.x = acc[0][i];
            x2.y = acc[1][i];
            cmax.x = fmaxf(cmax.x, x2.x);
            cmax.y = fmaxf(cmax.y, x2.y);
            f32x2 ax = x2 * 28.853900817779268f;
            f32x2 R, Ri, E4;
            R.x = __builtin_amdgcn_exp2f(ax.x);
            R.y = __builtin_amdgcn_exp2f(ax.y);
            Ri.x = __builtin_amdgcn_exp2f(-ax.x);    // indep of R: parallel chains
            Ri.y = __builtin_amdgcn_exp2f(-ax.y);
            f32x2 d4 = x2 + 0.1f;
            f32x2 t = d4 * d4 * (-72.134752044448169f);
            E4.x = __builtin_amdgcn_exp2f(t.x);
            E4.y = __builtin_amdgcn_exp2f(t.y);
            sums2[4] += E4;
            f32x2 u = E4 * R;
            sums2[5] += u;
            u *= R; sums2[6] += u;
            u *= R; sums2[7] += u;
            u *= R; sums2[8] += u;
            u *= R; sums2[9] += u;
            f32x2 w = E4 * Ri;
            sums2[3] += w;
            w *= Ri; sums2[2] += w;
            w *= Ri; sums2[1] += w;
            w *= Ri; sums2[0] += w;
        }
        if (__any(fmaxf(cmax.x, cmax.y) > 0.98f)) {   // ~never taken
            #pragma unroll
            for (int i = 0; i < 4; ++i) {
                f32x2 x2;
                x2.x = acc[0][i];
                x2.y = acc[1][i];
                f32x2 d1 = x2 - 1.0f;
                f32x2 t1 = d1 * d1 * (-721347.52044448f);
                f32x2 e;
                e.x = __builtin_amdgcn_exp2f(t1.x);
                e.y = __builtin_amdgcn_exp2f(t1.y);
                sums2[10] += e;
            }
        }

        __syncthreads();
        cur ^= 1;
    }

    #pragma unroll
    for (int k = 0; k < 11; ++k) {
        float s = sums2[k].x + sums2[k].y;
        s += __shfl_xor(s, 16);
        s += __shfl_xor(s, 32);
        sums2[k].x = s;
    }
    if ((lane >> 4) == 0) {
        #pragma unroll
        for (int k = 0; k < 11; ++k)
            red[wr][wc * 16 + (lane & 15)][k] = sums2[k].x;
    }
    __syncthreads();

    if (tid < 64) {
        const float scale[11] = {
            4.2483542552915889e-18f,  // e^-40
            3.7751345442790977e-11f,  // e^-24
            6.1442123533282098e-6f,   // e^-12
            1.8315638888734179e-2f,   // e^-4
            1.f, 1.f,
            1.8315638888734179e-2f,   // e^-4
            6.1442123533282098e-6f,   // e^-12
            3.7751345442790977e-11f,  // e^-24
            4.2483542552915889e-18f,  // e^-40
            1.f };
        float lv[11];
        #pragma unroll
        for (int k = 0; k < 11; ++k)
            lv[k] = log1pf(scale[k] * (red[0][tid][k] + red[1][tid][k]));
        #pragma unroll
        for (int k = 0; k < 11; ++k) {
            float s = lv[k];
            s += __shfl_xor(s, 1); s += __shfl_xor(s, 2); s += __shfl_xor(s, 4);
            s += __shfl_xor(s, 8); s += __shfl_xor(s, 16); s += __shfl_xor(s, 32);
            lv[k] = s;
        }
        if (tid == 0) {
            #pragma unroll
            for (int k = 0; k < 11; ++k)
                phi_part[(size_t)blk * 11 + k] = lv[k];
        }
    }
}

// ---------------- Stage 3: final linear (sums the two lq-half partials) -----
__global__ void final_kernel(const float* __restrict__ phi_part,
                             const float* __restrict__ ow,
                             const float* __restrict__ obias, float* __restrict__ out)
{
    int b = threadIdx.x;
    float s = obias[0];
    #pragma unroll
    for (int pair = 0; pair < 9; ++pair)
        #pragma unroll
        for (int k = 0; k < 11; ++k) {
            size_t base = ((size_t)b * 18 + pair * 2) * 11 + k;
            s += (phi_part[base] + phi_part[base + 11]) * ow[pair * 11 + k];
        }
    out[b] = s;
}

extern "C" void kernel_launch(void* const* d_in, const int* in_sizes, int n_in,
                              void* d_out, int out_size, void* d_ws, size_t ws_size,
                              hipStream_t stream)
{
    const int*   query = (const int*)d_in[0];
    const int*   doc   = (const int*)d_in[1];
    const float* q_emb = (const float*)d_in[2];
    const float* d_emb = (const float*)d_in[3];
    const float* out_w = (const float*)d_in[4];
    const float* out_b = (const float*)d_in[5];
    const float* cw0 = (const float*)d_in[6];
    const float* cb0 = (const float*)d_in[7];
    const float* cw1 = (const float*)d_in[8];
    const float* cb1 = (const float*)d_in[9];
    const float* cw2 = (const float*)d_in[10];
    const float* cb2 = (const float*)d_in[11];

    const size_t QN = (size_t)NB * NLQ * NH;
    const size_t DN = (size_t)NB * NLD * NH;
    const size_t XQN = (size_t)NB * XQROWS * XCOLS;
    const size_t XDN = (size_t)NB * XDROWS * XCOLS;

    bf16* Wp = (bf16*)d_ws;
    bf16* Xq = Wp + 368640;
    bf16* Xd = Xq + XQN;
    bf16* qn = Xd + XDN;
    bf16* dn = qn + 3 * QN;
    float* phi_part = (float*)(dn + 3 * DN);

    pack_all<<<7920, 256, 0, stream>>>(query, doc, q_emb, d_emb, cw0, cw1, cw2, Wp, Xq, Xd);
    conv_kernel<<<960, 512, 0, stream>>>(Xq, Xd, Wp, cb0, cb1, cb2, qn, dn);
    sim_kernel<<<NB * 9 * 2, 512, 0, stream>>>(qn, dn, phi_part);
    final_kernel<<<1, 128, 0, stream>>>(phi_part, out_w, out_b, (float*)d_out);
}